// Round 5
// baseline (268.246 us; speedup 1.0000x reference)
//
#include <hip/hip_runtime.h>
#include <cmath>

#define BLOCK 1024
#define NW 16
#define LISTCAP 16384
#define XLO -6.6f
#define CW 0.1f
#define ICW 10.0f
#define XHI 6.2f

#define LD4(j) (*(const float4*)(row + (j)))

// inclusive scan across a 64-lane wave (lane order = index order)
__device__ __forceinline__ float wincl(float v, int lane) {
#pragma unroll
    for (int o = 1; o < 64; o <<= 1) {
        float x = __shfl_up(v, o, 64);
        if (lane >= o) v += x;
    }
    return v;
}

// Walk buckets in DESCENDING order; find first bucket where running inclusive
// mass (starting at base0) exceeds limit. One full wave executes.
__device__ __forceinline__ void find_crit_desc(const float* h, int n, int seg,
                                               float base0, float limit, int lane,
                                               int* out_b, float* out_A) {
    float segsum = 0.f;
    int start = n - 1 - lane * seg;
    for (int k = 0; k < seg; k++) segsum += h[start - k];
    float incl = wincl(segsum, lane);
    unsigned long long mk = __ballot(base0 + incl > limit);
    if (mk == 0ULL) { *out_b = 0; *out_A = base0; return; }
    int fl = __ffsll(mk) - 1;
    float base = base0 + __shfl(incl, fl, 64) - __shfl(segsum, fl, 64);
    int sstart = n - 1 - fl * seg;
    float v = (lane < seg) ? h[sstart - lane] : 0.f;
    float incl2 = wincl(v, lane);
    unsigned long long mk2 = __ballot((lane < seg) && (base + incl2 > limit));
    int k2 = mk2 ? (__ffsll(mk2) - 1) : (seg - 1);
    *out_b = sstart - k2;
    *out_A = base + __shfl(incl2, k2, 64) - __shfl(v, k2, 64);
}

// monotone (total-order) key of a float's bit pattern
__device__ __forceinline__ unsigned okey(unsigned bits) {
    return (bits & 0x80000000u) ? ~bits : (bits | 0x80000000u);
}

__global__ __launch_bounds__(BLOCK) void NucleusSampling_79336635892529_kernel(
    const float* __restrict__ logits, const float* __restrict__ uvec,
    const int* __restrict__ temp, int* __restrict__ out, int Vv) {
    const int b = blockIdx.x;
    const float* __restrict__ row = logits + (size_t)b * (size_t)Vv;
    const int t = threadIdx.x;
    const int lane = t & 63;
    const int wave = t >> 6;

    __shared__ unsigned ch[4096];        // coarse hist (u32->f32), then fine hist
    __shared__ float sweep[NW];
    __shared__ unsigned csum_u[128];     // chunk sums, fixed-point 2^20
    __shared__ unsigned idxlist[LISTCAP];
    __shared__ int shi[1];
    __shared__ unsigned shu[1];
    __shared__ int cnt;

    const float invt = 1.0f / (float)temp[0];
    const float REF = XHI * invt;        // exponent shift: e^(x*invt - REF) <= ~1
    const int V4 = Vv & ~3;

    for (int i = t; i < 4096; i += BLOCK) ch[i] = 0u;
    if (t == 0) cnt = 0;
    if (t < 128) csum_u[t] = 0u;
    __syncthreads();

    // ---- P1: exact Z (no atomics) + 1/16-subsampled coarse hist (128 buckets)
    float zp = 0.f;
    {
        int g = 0;
        for (int i = t * 4; i + 3 < V4 + 1; i += BLOCK * 4, g++) {
            float4 v = LD4(i);
            float e0 = __expf(fmaf(v.x, invt, -REF));
            float e1 = __expf(fmaf(v.y, invt, -REF));
            float e2 = __expf(fmaf(v.z, invt, -REF));
            float e3 = __expf(fmaf(v.w, invt, -REF));
            zp += (e0 + e1) + (e2 + e3);
            if ((g & 3) == 0) {
                int bb = (int)((v.x - XLO) * ICW);
                bb = max(0, min(127, bb));
                atomicAdd(&ch[bb], (unsigned)(e0 * 262144.f + 0.5f)); // 2^18
            }
        }
        for (int j = V4 + t; j < Vv; j += BLOCK)
            zp += __expf(fmaf(row[j], invt, -REF));
    }
#pragma unroll
    for (int o = 32; o >= 1; o >>= 1) zp += __shfl_xor(zp, o, 64);
    if (lane == 0) sweep[wave] = zp;
    __syncthreads();
    float Z = 0.f;
    for (int w = 0; w < NW; w++) Z += sweep[w];
    const float limit = 0.9f * Z;

    // ---- Walk 0: coarse crossing bucket (subsample x16 scale)
    if (t < 128) {
        unsigned c = ch[t];
        ((float*)ch)[t] = (float)c * (16.f / 262144.f);
    }
    __syncthreads();
    if (wave == 0) {
        int c0w; float Aw;
        find_crit_desc((const float*)ch, 128, 2, 0.f, limit, lane, &c0w, &Aw);
        if (lane == 0) shi[0] = c0w;
    }
    __syncthreads();
    const int c0 = shi[0];
    const int blo_b = max(0, c0 - 1), bhi_b = min(127, c0 + 1);
    const float blo = XLO + (float)blo_b * CW;
    const float bandW = (float)(bhi_b - blo_b + 1) * CW;
    const float bhi = blo + bandW;
    for (int i = t; i < 4096; i += BLOCK) ch[i] = 0u;   // re-zero for fine hist
    __syncthreads();

    // ---- P2: chunk sums (keep b>=blo_b), exact above-band Sa, band compaction
    float sa = 0.f;
    const int nch = (Vv + 1023) >> 10;
#define PROC(xx, kk) { \
        int bb = (int)(((xx) - XLO) * ICW); bb = max(0, min(127, bb)); \
        float e = __expf(fmaf((xx), invt, -REF)); \
        if (bb >= blo_b) s += e; \
        if (bb > bhi_b) sa += e; \
        bool inb = (bb >= blo_b) && (bb <= bhi_b) && ((i0 + (kk)) < Vv); \
        unsigned long long mask = __ballot(inb); \
        if (mask) { int leader = __ffsll(mask) - 1; \
            if (inb) { int bpos = 0; \
                if (lane == leader) bpos = atomicAdd(&cnt, (int)__popcll(mask)); \
                bpos = __builtin_amdgcn_readfirstlane(bpos); \
                int pos = bpos + (int)__popcll(mask & ((1ull << lane) - 1ull)); \
                if (pos < LISTCAP) idxlist[pos] = (unsigned)(i0 + (kk)); } } }
    for (int c = wave; c < nch; c += NW) {
        float s = 0.f;
        const int base = c << 10;
#pragma unroll
        for (int q = 0; q < 4; q++) {
            int i0 = base + q * 256 + lane * 4;
            float x0, x1, x2, x3;
            if (i0 + 3 < Vv) {
                float4 v = LD4(i0);
                x0 = v.x; x1 = v.y; x2 = v.z; x3 = v.w;
            } else {
                x0 = (i0 < Vv) ? row[i0] : -1e30f;
                x1 = (i0 + 1 < Vv) ? row[i0 + 1] : -1e30f;
                x2 = (i0 + 2 < Vv) ? row[i0 + 2] : -1e30f;
                x3 = (i0 + 3 < Vv) ? row[i0 + 3] : -1e30f;
            }
            PROC(x0, 0) PROC(x1, 1) PROC(x2, 2) PROC(x3, 3)
        }
#pragma unroll
        for (int o = 32; o >= 1; o >>= 1) s += __shfl_xor(s, o, 64);
        if (lane == 0) csum_u[c] = (unsigned)(s * 1048576.f + 0.5f);  // 2^20
    }
#pragma unroll
    for (int o = 32; o >= 1; o >>= 1) sa += __shfl_xor(sa, o, 64);
    if (lane == 0) sweep[wave] = sa;
    __syncthreads();
    float Sa = 0.f;
    for (int w = 0; w < NW; w++) Sa += sweep[w];
    const int nlist = min(cnt, LISTCAP);

    // ---- Gather 1: fine hist (4096 bins over band) from compacted list
    const float binS = 4096.f / bandW;
    for (int p = t; p < nlist; p += BLOCK) {
        float x = row[idxlist[p]];
        int bin = (int)((x - blo) * binS);
        bin = max(0, min(4095, bin));
        float er = __expf((x - bhi) * invt);           // in (e^-0.3/t, 1]
        atomicAdd(&ch[bin], (unsigned)(er * 131072.f + 0.5f)); // 2^17
    }
    __syncthreads();
    const float CFc = __expf(fmaf(bhi, invt, -REF)) * (1.f / 131072.f);
    for (int i = t; i < 4096; i += BLOCK) {
        unsigned c = ch[i];
        ((float*)ch)[i] = (float)c * CFc;
    }
    __syncthreads();
    if (wave == 0) {
        int f0; float A2;
        find_crit_desc((const float*)ch, 4096, 64, Sa, limit, lane, &f0, &A2);
        if (lane == 0) {
            float Tx = blo + (float)f0 * (bandW * (1.f / 4096.f));
            shu[0] = okey(__float_as_uint(Tx));
        }
    }
    __syncthreads();
    const unsigned Tk = shu[0];   // keep <=> okey(bits(x)) >= Tk

    // ---- Gather 2: corrections — remove below-T band mass from chunk sums
    for (int p = t; p < nlist; p += BLOCK) {
        unsigned ii = idxlist[p];
        float x = row[ii];
        if (okey(__float_as_uint(x)) < Tk) {
            float e = __expf(fmaf(x, invt, -REF));
            atomicAdd(&csum_u[ii >> 10], (unsigned)(-(int)(e * 1048576.f + 0.5f)));
        }
    }
    __syncthreads();

    // ---- Final: locate token in the crossing chunk
    if (wave == 0) {
        auto rd = [&](int j) -> float {
            int v = (int)csum_u[j];
            return v > 0 ? (float)v * (1.f / 1048576.f) : 0.f;
        };
        float segsum = rd(lane * 2) + rd(lane * 2 + 1);
        float incl = wincl(segsum, lane);
        float total = __shfl(incl, 63, 64);            // Z_kept
        const float U = uvec[b] * total;
        unsigned long long mk = __ballot(incl >= U);
        int token;
        if (mk == 0ULL) {
            token = Vv;
        } else {
            int fl = __ffsll(mk) - 1;
            float base = __shfl(incl, fl, 64) - __shfl(segsum, fl, 64);
            float v = (lane < 2) ? rd(fl * 2 + lane) : 0.f;
            float incl2 = wincl(v, lane);
            unsigned long long mk2 = __ballot((lane < 2) && (base + incl2 >= U));
            int k2 = mk2 ? (__ffsll(mk2) - 1) : 1;
            int cx = fl * 2 + k2;                      // crossing chunk
            float B = base + __shfl(incl2, k2, 64) - __shfl(v, k2, 64);
            int cb = cx << 10;
            float vv[16];
#pragma unroll
            for (int r = 0; r < 16; r++) {
                int idx = cb + r * 64 + lane;
                vv[r] = (idx < Vv) ? row[idx] : -1e30f;
            }
            int cnt2 = 0;
#pragma unroll
            for (int r = 0; r < 16; r++) {
                int idx = cb + r * 64 + lane;
                unsigned kk = okey(__float_as_uint(vv[r]));
                float e = __expf(fmaf(vv[r], invt, -REF));
                float keep = (kk >= Tk) ? e : 0.f;
                float is = wincl(keep, lane);
                unsigned long long mm = __ballot((idx < Vv) && (B + is < U));
                cnt2 += __popcll(mm);
                B += __shfl(is, 63, 64);
            }
            token = cb + cnt2;
        }
        if (lane == 0) out[b] = (token < Vv - 1) ? token : (Vv - 1);
    }
}

extern "C" void kernel_launch(void* const* d_in, const int* in_sizes, int n_in,
                              void* d_out, int out_size, void* d_ws, size_t ws_size,
                              hipStream_t stream) {
    const float* logits = (const float*)d_in[0];
    const float* u = (const float*)d_in[1];
    const int* temp = (const int*)d_in[2];
    int* out = (int*)d_out;
    int B = in_sizes[1];
    int V = in_sizes[0] / B;
    NucleusSampling_79336635892529_kernel<<<B, BLOCK, 0, stream>>>(logits, u, temp, out, V);
}